// Round 3
// baseline (76.362 us; speedup 1.0000x reference)
//
#include <hip/hip_runtime.h>
#include <hip/hip_bf16.h>

#define GG    96     // grid size
#define DD    128    // feature dim
#define KC    32     // K-chunk = MFMA K
#define APAD  40     // padded LDS row stride in ushorts (80 B)
#define RCUT  21     // gaussian support radius in rows (sigma=4: exp(-21^2/32)=1e-6)

typedef __attribute__((ext_vector_type(8))) short short8v;  // 8 bf16 = 4 VGPRs
typedef __attribute__((ext_vector_type(4))) float f32x4;    // MFMA acc

// ---------------- Kernel 0: deterministic counting sort of nodes by floor(py) ----------------
// One block per batch. Produces pref[b][0..96] (bin prefix) and src[b*n_per+j] = orig node id.
__global__ __launch_bounds__(512) void sort_nodes(
    const float* __restrict__ pos, int* __restrict__ pref, int* __restrict__ src,
    int n_per)
{
    const int b = blockIdx.x;
    const int t = (int)threadIdx.x;
    __shared__ int hist[97];
    __shared__ int bins[512];
    __shared__ int spre[97];

    if (t < 97) hist[t] = 0;
    __syncthreads();

    const int n = b * n_per + t;
    const float py = pos[(size_t)n * 2 + 0];
    int bin = (int)floorf(py);
    bin = bin < 0 ? 0 : (bin > 95 ? 95 : bin);
    bins[t] = bin;
    atomicAdd(&hist[bin], 1);
    __syncthreads();

    if (t == 0) {
        int s = 0;
        for (int i = 0; i < 96; ++i) { spre[i] = s; s += hist[i]; }
        spre[96] = s;
    }
    __syncthreads();
    if (t < 97) pref[b * 97 + t] = spre[t];

    // stable rank within bin (deterministic: by original index)
    int r = 0;
    for (int j = 0; j < n_per; ++j) {
        int bj = bins[j];                 // broadcast read
        if (j < t && bj == bin) ++r;
    }
    src[b * n_per + spre[bin] + r] = n;
}

// ---------------- Kernel 1a: separable weights in PERMUTED order, transposed ----------------
__global__ __launch_bounds__(128) void node_weights_p(
    const float* __restrict__ pos, const float* __restrict__ log_sigma,
    const int* __restrict__ src,
    float* __restrict__ wygT, float* __restrict__ wxT, int Nn)
{
    const int j = blockIdx.x;            // permuted index
    const int n = src[j];
    const int t = threadIdx.x;
    const float py = pos[(size_t)n * 2 + 0], px = pos[(size_t)n * 2 + 1];
    const float sig = expf(log_sigma[0]);
    const float inv2s2 = 1.0f / (2.0f * sig * sig);
    float ey = 0.f, ex = 0.f;
    if (t < GG) {
        float dy = (float)t - py, dx = (float)t - px;
        ey = expf(-dy * dy * inv2s2);
        ex = expf(-dx * dx * inv2s2);
    }
    __shared__ float sy[128], sx[128];
    sy[t] = ey; sx[t] = ex;
    __syncthreads();
    for (int s = 64; s > 0; s >>= 1) {
        if (t < s) { sy[t] += sy[t + s]; sx[t] += sx[t + s]; }
        __syncthreads();
    }
    const float g = 1.0f / (sy[0] * sx[0] + 1e-8f);
    if (t < GG) {
        wygT[(size_t)t * Nn + j] = ey * g;
        wxT [(size_t)t * Nn + j] = ex;
    }
}

// ---------------- Kernel 1b: f gather-transpose-split into bf16 hi/lo, permuted ----------------
__global__ __launch_bounds__(256) void transpose_split_p(
    const float* __restrict__ f, const int* __restrict__ src,
    unsigned short* __restrict__ fTh, unsigned short* __restrict__ fTl, int Nn)
{
    __shared__ float sT[DD][33];
    __shared__ int sn[32];
    const int j0 = blockIdx.x * 32;
    const int t = (int)threadIdx.x;

    if (t < 32) sn[t] = src[j0 + t];
    __syncthreads();

#pragma unroll
    for (int jj = 0; jj < 4; ++jj) {
        int idx = t + 256 * jj;            // 0..1023
        int nl = idx >> 5;                 // 0..31 (permuted-local)
        int c  = idx & 31;                 // float4 column
        float4 v = *(const float4*)(f + (size_t)sn[nl] * DD + c * 4);
        sT[c * 4 + 0][nl] = v.x;
        sT[c * 4 + 1][nl] = v.y;
        sT[c * 4 + 2][nl] = v.z;
        sT[c * 4 + 3][nl] = v.w;
    }
    __syncthreads();

    const int d = t >> 1, h = t & 1;
    unsigned int ph[8], pl[8];
#pragma unroll
    for (int q = 0; q < 8; ++q) {
        float x0 = sT[d][h * 16 + 2 * q];
        float x1 = sT[d][h * 16 + 2 * q + 1];
        __hip_bfloat16 h0 = __float2bfloat16(x0);
        __hip_bfloat16 h1 = __float2bfloat16(x1);
        __hip_bfloat16 l0 = __float2bfloat16(x0 - __bfloat162float(h0));
        __hip_bfloat16 l1 = __float2bfloat16(x1 - __bfloat162float(h1));
        unsigned short uh0 = *(const unsigned short*)&h0;
        unsigned short uh1 = *(const unsigned short*)&h1;
        unsigned short ul0 = *(const unsigned short*)&l0;
        unsigned short ul1 = *(const unsigned short*)&l1;
        ph[q] = (unsigned int)uh0 | ((unsigned int)uh1 << 16);
        pl[q] = (unsigned int)ul0 | ((unsigned int)ul1 << 16);
    }
    int4* dh = (int4*)(fTh + (size_t)d * Nn + j0 + h * 16);
    int4* dl = (int4*)(fTl + (size_t)d * Nn + j0 + h * 16);
    dh[0] = make_int4((int)ph[0], (int)ph[1], (int)ph[2], (int)ph[3]);
    dh[1] = make_int4((int)ph[4], (int)ph[5], (int)ph[6], (int)ph[7]);
    dl[0] = make_int4((int)pl[0], (int)pl[1], (int)pl[2], (int)pl[3]);
    dl[1] = make_int4((int)pl[4], (int)pl[5], (int)pl[6], (int)pl[7]);
}

// ---------------- Kernel 2: MFMA splat GEMM with y-band K-pruning ----------------
__global__ __launch_bounds__(256, 3) void splat_mfma(
    const unsigned short* __restrict__ fTh, const unsigned short* __restrict__ fTl,
    const float* __restrict__ wygT, const float* __restrict__ wxT,
    const int* __restrict__ pref,
    float* __restrict__ out, int Nn, int n_per)
{
    const int b = blockIdx.x;
    const int y = blockIdx.y;
    const int tid = (int)threadIdx.x;
    const int lane = tid & 63;
    const int wid  = tid >> 6;
    const int lr = lane & 15;
    const int kg = lane >> 4;

    __shared__ __align__(16) unsigned short sAh[DD][APAD];
    __shared__ __align__(16) unsigned short sAl[DD][APAD];
    __shared__ __align__(16) unsigned short sW [GG][APAD];

    f32x4 acc[2][6];
#pragma unroll
    for (int mi = 0; mi < 2; ++mi)
#pragma unroll
        for (int ni = 0; ni < 6; ++ni) acc[mi][ni] = (f32x4){0.f, 0.f, 0.f, 0.f};

    // K-range from sorted-bin prefix: bins [y-RCUT, y+RCUT-1] cover all py with |py-y|<RCUT
    const int lob = y - RCUT < 0 ? 0 : y - RCUT;
    const int hib = y + RCUT > 96 ? 96 : y + RCUT;
    const int klo = pref[b * 97 + lob];
    const int khi = pref[b * 97 + hib];
    const int c0 = klo >> 5;
    const int c1 = (khi + 31) >> 5;

    const int nbase = b * n_per;
    const float* wyrow = wygT + (size_t)y * Nn;
    const int sd = tid >> 1, sh = tid & 1;

    int4 va0, va1, vb0, vb1;
    if (c0 < c1) {
        const unsigned short* srcH = fTh + (size_t)sd * Nn + nbase + c0 * KC + sh * 16;
        const unsigned short* srcL = fTl + (size_t)sd * Nn + nbase + c0 * KC + sh * 16;
        va0 = ((const int4*)srcH)[0]; va1 = ((const int4*)srcH)[1];
        vb0 = ((const int4*)srcL)[0]; vb1 = ((const int4*)srcL)[1];
    }

    for (int c = c0; c < c1; ++c) {
        const int ncur = nbase + c * KC;

        {
            int4* dA = (int4*)&sAh[sd][sh * 16];
            dA[0] = va0; dA[1] = va1;
            int4* dB = (int4*)&sAl[sd][sh * 16];
            dB[0] = vb0; dB[1] = vb1;
        }
#pragma unroll
        for (int i = 0; i < 6; ++i) {
            int p  = tid + 256 * i;
            int x  = p >> 4;
            int kp = p & 15;
            float2 wy = *(const float2*)(wyrow + ncur + 2 * kp);
            float2 wx = *(const float2*)(wxT + (size_t)x * Nn + ncur + 2 * kp);
            float w0 = wy.x * wx.x, w1 = wy.y * wx.y;
            __hip_bfloat16 b0 = __float2bfloat16(w0);
            __hip_bfloat16 b1 = __float2bfloat16(w1);
            unsigned int u = (unsigned int)(*(const unsigned short*)&b0)
                           | ((unsigned int)(*(const unsigned short*)&b1) << 16);
            *(unsigned int*)&sW[x][2 * kp] = u;
        }
        __syncthreads();

        if (c + 1 < c1) {
            const int nn = nbase + (c + 1) * KC;
            const unsigned short* srcH = fTh + (size_t)sd * Nn + nn + sh * 16;
            const unsigned short* srcL = fTl + (size_t)sd * Nn + nn + sh * 16;
            va0 = ((const int4*)srcH)[0]; va1 = ((const int4*)srcH)[1];
            vb0 = ((const int4*)srcL)[0]; vb1 = ((const int4*)srcL)[1];
        }

        const int ar0 = wid * 32 + lr;
        short8v ah0 = *(const short8v*)&sAh[ar0][kg * 8];
        short8v ah1 = *(const short8v*)&sAh[ar0 + 16][kg * 8];
        short8v al0 = *(const short8v*)&sAl[ar0][kg * 8];
        short8v al1 = *(const short8v*)&sAl[ar0 + 16][kg * 8];
#pragma unroll
        for (int ni = 0; ni < 6; ++ni) {
            short8v bv = *(const short8v*)&sW[ni * 16 + lr][kg * 8];
            acc[0][ni] = __builtin_amdgcn_mfma_f32_16x16x32_bf16(ah0, bv, acc[0][ni], 0, 0, 0);
            acc[1][ni] = __builtin_amdgcn_mfma_f32_16x16x32_bf16(ah1, bv, acc[1][ni], 0, 0, 0);
            acc[0][ni] = __builtin_amdgcn_mfma_f32_16x16x32_bf16(al0, bv, acc[0][ni], 0, 0, 0);
            acc[1][ni] = __builtin_amdgcn_mfma_f32_16x16x32_bf16(al1, bv, acc[1][ni], 0, 0, 0);
        }
        __syncthreads();
    }

#pragma unroll
    for (int mi = 0; mi < 2; ++mi)
#pragma unroll
        for (int ni = 0; ni < 6; ++ni) {
            const int d0 = wid * 32 + mi * 16 + kg * 4;
            const int x  = ni * 16 + lr;
            float* op = out + (((size_t)b * DD + d0) * GG + y) * GG + x;
#pragma unroll
            for (int r = 0; r < 4; ++r)
                op[(size_t)r * GG * GG] = acc[mi][ni][r];
        }
}

extern "C" void kernel_launch(void* const* d_in, const int* in_sizes, int n_in,
                              void* d_out, int out_size, void* d_ws, size_t ws_size,
                              hipStream_t stream) {
    const float* feat = (const float*)d_in[0];
    const float* pos  = (const float*)d_in[1];
    const float* lsig = (const float*)d_in[4];

    const int N  = in_sizes[2];                        // 4096
    const int B  = out_size / (DD * GG * GG);          // 8
    const int n_per = N / B;                           // 512

    int* pref = (int*)d_ws;                            // B x 97
    int* src  = pref + B * 97;                         // N
    float* wygT = (float*)(src + N);                   // 96 x N f32
    float* wxT  = wygT + (size_t)GG * N;               // 96 x N f32
    unsigned short* fTh = (unsigned short*)(wxT + (size_t)GG * N);  // 128 x N bf16
    unsigned short* fTl = fTh + (size_t)DD * N;                     // 128 x N bf16

    sort_nodes<<<B, n_per, 0, stream>>>(pos, pref, src, n_per);
    node_weights_p<<<N, 128, 0, stream>>>(pos, lsig, src, wygT, wxT, N);
    transpose_split_p<<<N / 32, 256, 0, stream>>>(feat, src, fTh, fTl, N);

    dim3 g2(B, GG);
    splat_mfma<<<g2, 256, 0, stream>>>(fTh, fTl, wygT, wxT, pref, (float*)d_out, N, n_per);
}

// Round 4
// 48.034 us; speedup vs baseline: 1.5897x; 1.5897x over previous
//
#include <hip/hip_runtime.h>
#include <hip/hip_bf16.h>

#define GG    96     // grid size
#define DD    128    // feature dim
#define KC    32     // K-chunk = MFMA K
#define APAD  40     // padded LDS row stride in ushorts (80 B)
#define RCUT  21     // gaussian support radius in rows (sigma=4: exp(-21^2/32)=1e-6)

typedef __attribute__((ext_vector_type(8))) short short8v;  // 8 bf16 = 4 VGPRs
typedef __attribute__((ext_vector_type(4))) float f32x4;    // MFMA acc

// ---------------- Kernel 0: deterministic counting sort of nodes by floor(py) ----------------
// One block per batch (512 threads = 8 waves). Ballot-based stable rank: no serial loops.
__global__ __launch_bounds__(512) void sort_nodes(
    const float* __restrict__ pos, int* __restrict__ pref, int* __restrict__ src,
    int n_per)
{
    const int b = blockIdx.x;
    const int t = (int)threadIdx.x;
    const int w = t >> 6, lane = t & 63;

    __shared__ int whist[8][GG];   // per-wave bin counts
    __shared__ int wpart[8][GG];   // exclusive prefix of whist across waves, per bin
    __shared__ int spre[GG + 1];   // global bin prefix

    for (int i = t; i < 8 * GG; i += 512) (&whist[0][0])[i] = 0;
    __syncthreads();

    const int n = b * n_per + t;
    int bin = (int)floorf(pos[(size_t)n * 2 + 0]);
    bin = bin < 0 ? 0 : (bin > GG - 1 ? GG - 1 : bin);
    atomicAdd(&whist[w][bin], 1);   // counts: order-independent -> deterministic

    // same-bin lanes within my wave via bitwise ballot match (bins fit in 7 bits)
    unsigned long long mask = ~0ull;
#pragma unroll
    for (int bit = 0; bit < 7; ++bit) {
        unsigned long long bb = __ballot((bin >> bit) & 1);
        mask &= ((bin >> bit) & 1) ? bb : ~bb;
    }
    const int rank = __popcll(mask & ((lane == 0) ? 0ull : (~0ull >> (64 - lane))));
    __syncthreads();

    // cross-wave offsets per bin + bin totals
    if (t < GG) {
        int s = 0;
#pragma unroll
        for (int ww = 0; ww < 8; ++ww) { wpart[ww][t] = s; s += whist[ww][t]; }
        spre[t + 1] = s;            // bin count (temporarily)
    }
    __syncthreads();
    if (t == 0) {
        int s = 0;
        spre[0] = 0;
        for (int i = 1; i <= GG; ++i) { s += spre[i]; spre[i] = s; }
    }
    __syncthreads();

    if (t < GG + 1) pref[b * (GG + 1) + t] = spre[t];
    src[b * n_per + spre[bin] + wpart[w][bin] + rank] = n;
}

// ---------------- Kernel 1a: separable weights in PERMUTED order, transposed ----------------
__global__ __launch_bounds__(128) void node_weights_p(
    const float* __restrict__ pos, const float* __restrict__ log_sigma,
    const int* __restrict__ src,
    float* __restrict__ wygT, float* __restrict__ wxT, int Nn)
{
    const int j = blockIdx.x;            // permuted index
    const int n = src[j];
    const int t = threadIdx.x;
    const float py = pos[(size_t)n * 2 + 0], px = pos[(size_t)n * 2 + 1];
    const float sig = expf(log_sigma[0]);
    const float inv2s2 = 1.0f / (2.0f * sig * sig);
    float ey = 0.f, ex = 0.f;
    if (t < GG) {
        float dy = (float)t - py, dx = (float)t - px;
        ey = expf(-dy * dy * inv2s2);
        ex = expf(-dx * dx * inv2s2);
    }
    __shared__ float sy[128], sx[128];
    sy[t] = ey; sx[t] = ex;
    __syncthreads();
    for (int s = 64; s > 0; s >>= 1) {
        if (t < s) { sy[t] += sy[t + s]; sx[t] += sx[t + s]; }
        __syncthreads();
    }
    const float g = 1.0f / (sy[0] * sx[0] + 1e-8f);
    if (t < GG) {
        wygT[(size_t)t * Nn + j] = ey * g;
        wxT [(size_t)t * Nn + j] = ex;
    }
}

// ---------------- Kernel 1b: f gather-transpose-split into bf16 hi/lo, permuted ----------------
__global__ __launch_bounds__(256) void transpose_split_p(
    const float* __restrict__ f, const int* __restrict__ src,
    unsigned short* __restrict__ fTh, unsigned short* __restrict__ fTl, int Nn)
{
    __shared__ float sT[DD][33];
    __shared__ int sn[32];
    const int j0 = blockIdx.x * 32;
    const int t = (int)threadIdx.x;

    if (t < 32) sn[t] = src[j0 + t];
    __syncthreads();

#pragma unroll
    for (int jj = 0; jj < 4; ++jj) {
        int idx = t + 256 * jj;            // 0..1023
        int nl = idx >> 5;                 // 0..31 (permuted-local)
        int c  = idx & 31;                 // float4 column
        float4 v = *(const float4*)(f + (size_t)sn[nl] * DD + c * 4);
        sT[c * 4 + 0][nl] = v.x;
        sT[c * 4 + 1][nl] = v.y;
        sT[c * 4 + 2][nl] = v.z;
        sT[c * 4 + 3][nl] = v.w;
    }
    __syncthreads();

    const int d = t >> 1, h = t & 1;
    unsigned int ph[8], pl[8];
#pragma unroll
    for (int q = 0; q < 8; ++q) {
        float x0 = sT[d][h * 16 + 2 * q];
        float x1 = sT[d][h * 16 + 2 * q + 1];
        __hip_bfloat16 h0 = __float2bfloat16(x0);
        __hip_bfloat16 h1 = __float2bfloat16(x1);
        __hip_bfloat16 l0 = __float2bfloat16(x0 - __bfloat162float(h0));
        __hip_bfloat16 l1 = __float2bfloat16(x1 - __bfloat162float(h1));
        unsigned short uh0 = *(const unsigned short*)&h0;
        unsigned short uh1 = *(const unsigned short*)&h1;
        unsigned short ul0 = *(const unsigned short*)&l0;
        unsigned short ul1 = *(const unsigned short*)&l1;
        ph[q] = (unsigned int)uh0 | ((unsigned int)uh1 << 16);
        pl[q] = (unsigned int)ul0 | ((unsigned int)ul1 << 16);
    }
    int4* dh = (int4*)(fTh + (size_t)d * Nn + j0 + h * 16);
    int4* dl = (int4*)(fTl + (size_t)d * Nn + j0 + h * 16);
    dh[0] = make_int4((int)ph[0], (int)ph[1], (int)ph[2], (int)ph[3]);
    dh[1] = make_int4((int)ph[4], (int)ph[5], (int)ph[6], (int)ph[7]);
    dl[0] = make_int4((int)pl[0], (int)pl[1], (int)pl[2], (int)pl[3]);
    dl[1] = make_int4((int)pl[4], (int)pl[5], (int)pl[6], (int)pl[7]);
}

// ---------------- Kernel 2: MFMA splat GEMM with y-band K-pruning ----------------
__global__ __launch_bounds__(256, 3) void splat_mfma(
    const unsigned short* __restrict__ fTh, const unsigned short* __restrict__ fTl,
    const float* __restrict__ wygT, const float* __restrict__ wxT,
    const int* __restrict__ pref,
    float* __restrict__ out, int Nn, int n_per)
{
    const int b = blockIdx.x;
    const int y = blockIdx.y;
    const int tid = (int)threadIdx.x;
    const int lane = tid & 63;
    const int wid  = tid >> 6;
    const int lr = lane & 15;
    const int kg = lane >> 4;

    __shared__ __align__(16) unsigned short sAh[DD][APAD];
    __shared__ __align__(16) unsigned short sAl[DD][APAD];
    __shared__ __align__(16) unsigned short sW [GG][APAD];

    f32x4 acc[2][6];
#pragma unroll
    for (int mi = 0; mi < 2; ++mi)
#pragma unroll
        for (int ni = 0; ni < 6; ++ni) acc[mi][ni] = (f32x4){0.f, 0.f, 0.f, 0.f};

    // K-range from sorted-bin prefix: bins [y-RCUT, y+RCUT-1] cover all py with |py-y|<RCUT
    const int lob = y - RCUT < 0 ? 0 : y - RCUT;
    const int hib = y + RCUT > GG ? GG : y + RCUT;
    const int klo = pref[b * (GG + 1) + lob];
    const int khi = pref[b * (GG + 1) + hib];
    const int c0 = klo >> 5;
    const int c1 = (khi + 31) >> 5;

    const int nbase = b * n_per;
    const float* wyrow = wygT + (size_t)y * Nn;
    const int sd = tid >> 1, sh = tid & 1;

    int4 va0, va1, vb0, vb1;
    if (c0 < c1) {
        const unsigned short* srcH = fTh + (size_t)sd * Nn + nbase + c0 * KC + sh * 16;
        const unsigned short* srcL = fTl + (size_t)sd * Nn + nbase + c0 * KC + sh * 16;
        va0 = ((const int4*)srcH)[0]; va1 = ((const int4*)srcH)[1];
        vb0 = ((const int4*)srcL)[0]; vb1 = ((const int4*)srcL)[1];
    }

    for (int c = c0; c < c1; ++c) {
        const int ncur = nbase + c * KC;

        {
            int4* dA = (int4*)&sAh[sd][sh * 16];
            dA[0] = va0; dA[1] = va1;
            int4* dB = (int4*)&sAl[sd][sh * 16];
            dB[0] = vb0; dB[1] = vb1;
        }
#pragma unroll
        for (int i = 0; i < 6; ++i) {
            int p  = tid + 256 * i;
            int x  = p >> 4;
            int kp = p & 15;
            float2 wy = *(const float2*)(wyrow + ncur + 2 * kp);
            float2 wx = *(const float2*)(wxT + (size_t)x * Nn + ncur + 2 * kp);
            float w0 = wy.x * wx.x, w1 = wy.y * wx.y;
            __hip_bfloat16 b0 = __float2bfloat16(w0);
            __hip_bfloat16 b1 = __float2bfloat16(w1);
            unsigned int u = (unsigned int)(*(const unsigned short*)&b0)
                           | ((unsigned int)(*(const unsigned short*)&b1) << 16);
            *(unsigned int*)&sW[x][2 * kp] = u;
        }
        __syncthreads();

        if (c + 1 < c1) {
            const int nn = nbase + (c + 1) * KC;
            const unsigned short* srcH = fTh + (size_t)sd * Nn + nn + sh * 16;
            const unsigned short* srcL = fTl + (size_t)sd * Nn + nn + sh * 16;
            va0 = ((const int4*)srcH)[0]; va1 = ((const int4*)srcH)[1];
            vb0 = ((const int4*)srcL)[0]; vb1 = ((const int4*)srcL)[1];
        }

        const int ar0 = wid * 32 + lr;
        short8v ah0 = *(const short8v*)&sAh[ar0][kg * 8];
        short8v ah1 = *(const short8v*)&sAh[ar0 + 16][kg * 8];
        short8v al0 = *(const short8v*)&sAl[ar0][kg * 8];
        short8v al1 = *(const short8v*)&sAl[ar0 + 16][kg * 8];
#pragma unroll
        for (int ni = 0; ni < 6; ++ni) {
            short8v bv = *(const short8v*)&sW[ni * 16 + lr][kg * 8];
            acc[0][ni] = __builtin_amdgcn_mfma_f32_16x16x32_bf16(ah0, bv, acc[0][ni], 0, 0, 0);
            acc[1][ni] = __builtin_amdgcn_mfma_f32_16x16x32_bf16(ah1, bv, acc[1][ni], 0, 0, 0);
            acc[0][ni] = __builtin_amdgcn_mfma_f32_16x16x32_bf16(al0, bv, acc[0][ni], 0, 0, 0);
            acc[1][ni] = __builtin_amdgcn_mfma_f32_16x16x32_bf16(al1, bv, acc[1][ni], 0, 0, 0);
        }
        __syncthreads();
    }

#pragma unroll
    for (int mi = 0; mi < 2; ++mi)
#pragma unroll
        for (int ni = 0; ni < 6; ++ni) {
            const int d0 = wid * 32 + mi * 16 + kg * 4;
            const int x  = ni * 16 + lr;
            float* op = out + (((size_t)b * DD + d0) * GG + y) * GG + x;
#pragma unroll
            for (int r = 0; r < 4; ++r)
                op[(size_t)r * GG * GG] = acc[mi][ni][r];
        }
}

extern "C" void kernel_launch(void* const* d_in, const int* in_sizes, int n_in,
                              void* d_out, int out_size, void* d_ws, size_t ws_size,
                              hipStream_t stream) {
    const float* feat = (const float*)d_in[0];
    const float* pos  = (const float*)d_in[1];
    const float* lsig = (const float*)d_in[4];

    const int N  = in_sizes[2];                        // 4096
    const int B  = out_size / (DD * GG * GG);          // 8
    const int n_per = N / B;                           // 512

    int* pref = (int*)d_ws;                            // B x 97
    int* src  = pref + B * (GG + 1);                   // N
    float* wygT = (float*)(src + N);                   // 96 x N f32
    float* wxT  = wygT + (size_t)GG * N;               // 96 x N f32
    unsigned short* fTh = (unsigned short*)(wxT + (size_t)GG * N);  // 128 x N bf16
    unsigned short* fTl = fTh + (size_t)DD * N;                     // 128 x N bf16

    sort_nodes<<<B, n_per, 0, stream>>>(pos, pref, src, n_per);
    node_weights_p<<<N, 128, 0, stream>>>(pos, lsig, src, wygT, wxT, N);
    transpose_split_p<<<N / 32, 256, 0, stream>>>(feat, src, fTh, fTl, N);

    dim3 g2(B, GG);
    splat_mfma<<<g2, 256, 0, stream>>>(fTh, fTl, wygT, wxT, pref, (float*)d_out, N, n_per);
}

// Round 5
// 43.673 us; speedup vs baseline: 1.7485x; 1.0999x over previous
//
#include <hip/hip_runtime.h>
#include <hip/hip_bf16.h>

#define GG    96     // grid size
#define DD    128    // feature dim
#define KC    32     // K-chunk = MFMA K
#define APAD  40     // padded LDS row stride in ushorts (80 B)
#define RCUT  21     // gaussian support radius in rows (sigma=4: exp(-21^2/32)=1e-6)

typedef __attribute__((ext_vector_type(8))) short short8v;  // 8 bf16 = 4 VGPRs
typedef __attribute__((ext_vector_type(4))) float f32x4;    // MFMA acc

// ---------------- Kernel 0: deterministic counting sort of nodes by floor(py) ----------------
__global__ __launch_bounds__(512) void sort_nodes(
    const float* __restrict__ pos, int* __restrict__ pref, int* __restrict__ src,
    int n_per)
{
    const int b = blockIdx.x;
    const int t = (int)threadIdx.x;
    const int w = t >> 6, lane = t & 63;

    __shared__ int whist[8][GG];
    __shared__ int wpart[8][GG];
    __shared__ int spre[GG + 1];

    for (int i = t; i < 8 * GG; i += 512) (&whist[0][0])[i] = 0;
    __syncthreads();

    const int n = b * n_per + t;
    int bin = (int)floorf(pos[(size_t)n * 2 + 0]);
    bin = bin < 0 ? 0 : (bin > GG - 1 ? GG - 1 : bin);
    atomicAdd(&whist[w][bin], 1);

    unsigned long long mask = ~0ull;
#pragma unroll
    for (int bit = 0; bit < 7; ++bit) {
        unsigned long long bb = __ballot((bin >> bit) & 1);
        mask &= ((bin >> bit) & 1) ? bb : ~bb;
    }
    const int rank = __popcll(mask & ((lane == 0) ? 0ull : (~0ull >> (64 - lane))));
    __syncthreads();

    if (t < GG) {
        int s = 0;
#pragma unroll
        for (int ww = 0; ww < 8; ++ww) { wpart[ww][t] = s; s += whist[ww][t]; }
        spre[t + 1] = s;
    }
    __syncthreads();
    if (t == 0) {
        int s = 0;
        spre[0] = 0;
        for (int i = 1; i <= GG; ++i) { s += spre[i]; spre[i] = s; }
    }
    __syncthreads();

    if (t < GG + 1) pref[b * (GG + 1) + t] = spre[t];
    src[b * n_per + spre[bin] + wpart[w][bin] + rank] = n;
}

// ---------------- Kernel 1a: separable weights, tiled + coalesced writes ----------------
// Block = 32 permuted nodes x 96 rows. thread (g=t>>5, c=t&31) computes rows y=r*8+g.
__global__ __launch_bounds__(256) void node_weights_p(
    const float* __restrict__ pos, const float* __restrict__ log_sigma,
    const int* __restrict__ src,
    float* __restrict__ wygT, float* __restrict__ wxT, int Nn)
{
    const int j0 = blockIdx.x * 32;
    const int t = (int)threadIdx.x;
    const int g = t >> 5, c = t & 31;

    __shared__ float sE[GG][32];
    __shared__ float sX[GG][32];
    __shared__ float sPy[8][32], sPx[8][32];
    __shared__ float spy[32], spx[32];
    __shared__ float sG[32];

    if (t < 32) {
        int n = src[j0 + t];
        spy[t] = pos[(size_t)n * 2 + 0];
        spx[t] = pos[(size_t)n * 2 + 1];
    }
    __syncthreads();

    const float sig = expf(log_sigma[0]);
    const float inv2s2 = 1.0f / (2.0f * sig * sig);
    const float py = spy[c], px = spx[c];

    float pey = 0.f, pex = 0.f;
#pragma unroll
    for (int r = 0; r < 12; ++r) {
        int yy = r * 8 + g;
        float dy = (float)yy - py;
        float dx = (float)yy - px;
        float ey = expf(-dy * dy * inv2s2);
        float ex = expf(-dx * dx * inv2s2);
        sE[yy][c] = ey; sX[yy][c] = ex;
        pey += ey; pex += ex;
    }
    sPy[g][c] = pey; sPx[g][c] = pex;
    __syncthreads();

    if (t < 32) {
        float sy = 0.f, sx = 0.f;
#pragma unroll
        for (int ww = 0; ww < 8; ++ww) { sy += sPy[ww][t]; sx += sPx[ww][t]; }
        sG[t] = 1.0f / (sy * sx + 1e-8f);
    }
    __syncthreads();

    const float gf = sG[c];
#pragma unroll
    for (int r = 0; r < 12; ++r) {
        int yy = r * 8 + g;
        wygT[(size_t)yy * Nn + j0 + c] = sE[yy][c] * gf;
        wxT [(size_t)yy * Nn + j0 + c] = sX[yy][c];
    }
}

// ---------------- Kernel 1b: f gather-transpose-split into bf16 hi/lo, permuted ----------------
__global__ __launch_bounds__(256) void transpose_split_p(
    const float* __restrict__ f, const int* __restrict__ src,
    unsigned short* __restrict__ fTh, unsigned short* __restrict__ fTl, int Nn)
{
    __shared__ float sT[DD][33];
    __shared__ int sn[32];
    const int j0 = blockIdx.x * 32;
    const int t = (int)threadIdx.x;

    if (t < 32) sn[t] = src[j0 + t];
    __syncthreads();

#pragma unroll
    for (int jj = 0; jj < 4; ++jj) {
        int idx = t + 256 * jj;
        int nl = idx >> 5;
        int c  = idx & 31;
        float4 v = *(const float4*)(f + (size_t)sn[nl] * DD + c * 4);
        sT[c * 4 + 0][nl] = v.x;
        sT[c * 4 + 1][nl] = v.y;
        sT[c * 4 + 2][nl] = v.z;
        sT[c * 4 + 3][nl] = v.w;
    }
    __syncthreads();

    const int d = t >> 1, h = t & 1;
    unsigned int ph[8], pl[8];
#pragma unroll
    for (int q = 0; q < 8; ++q) {
        float x0 = sT[d][h * 16 + 2 * q];
        float x1 = sT[d][h * 16 + 2 * q + 1];
        __hip_bfloat16 h0 = __float2bfloat16(x0);
        __hip_bfloat16 h1 = __float2bfloat16(x1);
        __hip_bfloat16 l0 = __float2bfloat16(x0 - __bfloat162float(h0));
        __hip_bfloat16 l1 = __float2bfloat16(x1 - __bfloat162float(h1));
        unsigned short uh0 = *(const unsigned short*)&h0;
        unsigned short uh1 = *(const unsigned short*)&h1;
        unsigned short ul0 = *(const unsigned short*)&l0;
        unsigned short ul1 = *(const unsigned short*)&l1;
        ph[q] = (unsigned int)uh0 | ((unsigned int)uh1 << 16);
        pl[q] = (unsigned int)ul0 | ((unsigned int)ul1 << 16);
    }
    int4* dh = (int4*)(fTh + (size_t)d * Nn + j0 + h * 16);
    int4* dl = (int4*)(fTl + (size_t)d * Nn + j0 + h * 16);
    dh[0] = make_int4((int)ph[0], (int)ph[1], (int)ph[2], (int)ph[3]);
    dh[1] = make_int4((int)ph[4], (int)ph[5], (int)ph[6], (int)ph[7]);
    dl[0] = make_int4((int)pl[0], (int)pl[1], (int)pl[2], (int)pl[3]);
    dl[1] = make_int4((int)pl[4], (int)pl[5], (int)pl[6], (int)pl[7]);
}

// ---------------- Kernel 2: MFMA splat GEMM, direct-gather A, dbuf W, 1 barrier/chunk ----------------
__global__ __launch_bounds__(256, 3) void splat_mfma(
    const unsigned short* __restrict__ fTh, const unsigned short* __restrict__ fTl,
    const float* __restrict__ wygT, const float* __restrict__ wxT,
    const int* __restrict__ pref,
    float* __restrict__ out, int Nn, int n_per)
{
    const int b = blockIdx.x;
    const int y = blockIdx.y;
    const int tid = (int)threadIdx.x;
    const int lane = tid & 63;
    const int wid  = tid >> 6;
    const int lr = lane & 15;
    const int kg = lane >> 4;

    __shared__ __align__(16) unsigned short sW[2][GG][APAD];  // 15 KiB, double-buffered

    f32x4 acc[2][6];
#pragma unroll
    for (int mi = 0; mi < 2; ++mi)
#pragma unroll
        for (int ni = 0; ni < 6; ++ni) acc[mi][ni] = (f32x4){0.f, 0.f, 0.f, 0.f};

    const int lob = y - RCUT < 0 ? 0 : y - RCUT;
    const int hib = y + RCUT > GG ? GG : y + RCUT;
    const int klo = pref[b * (GG + 1) + lob];
    const int khi = pref[b * (GG + 1) + hib];
    const int c0 = klo >> 5;
    const int c1 = (khi + 31) >> 5;

    const int nbase = b * n_per;
    const float* wyrow = wygT + (size_t)y * Nn;

    // A fragment row base: rows ar0 and ar0+16 of fT, hi and lo
    const int ar0 = wid * 32 + lr;
    const unsigned short* pH0 = fTh + (size_t)ar0 * Nn;
    const unsigned short* pH1 = fTh + (size_t)(ar0 + 16) * Nn;
    const unsigned short* pL0 = fTl + (size_t)ar0 * Nn;
    const unsigned short* pL1 = fTl + (size_t)(ar0 + 16) * Nn;

#define WGEN(CC, BUF)                                                              \
    {                                                                              \
        const int ncur_ = nbase + (CC) * KC;                                       \
        _Pragma("unroll")                                                          \
        for (int i_ = 0; i_ < 6; ++i_) {                                           \
            int p_  = tid + 256 * i_;                                              \
            int x_  = p_ >> 4;                                                     \
            int kp_ = p_ & 15;                                                     \
            float2 wy_ = *(const float2*)(wyrow + ncur_ + 2 * kp_);                \
            float2 wx_ = *(const float2*)(wxT + (size_t)x_ * Nn + ncur_ + 2 * kp_);\
            float w0_ = wy_.x * wx_.x, w1_ = wy_.y * wx_.y;                        \
            __hip_bfloat16 b0_ = __float2bfloat16(w0_);                            \
            __hip_bfloat16 b1_ = __float2bfloat16(w1_);                            \
            unsigned int u_ = (unsigned int)(*(const unsigned short*)&b0_)         \
                            | ((unsigned int)(*(const unsigned short*)&b1_) << 16);\
            *(unsigned int*)&sW[BUF][x_][2 * kp_] = u_;                            \
        }                                                                          \
    }

    short8v cah0 = {}, cah1 = {}, cal0 = {}, cal1 = {};
    if (c0 < c1) {
        WGEN(c0, 0);
        const int k0 = nbase + c0 * KC + kg * 8;
        cah0 = *(const short8v*)(pH0 + k0);
        cah1 = *(const short8v*)(pH1 + k0);
        cal0 = *(const short8v*)(pL0 + k0);
        cal1 = *(const short8v*)(pL1 + k0);
    }
    __syncthreads();

    int cur = 0;
    for (int c = c0; c < c1; ++c) {
        // prefetch next chunk's A frags + generate next W tile (into other buffer)
        short8v nah0 = cah0, nah1 = cah1, nal0 = cal0, nal1 = cal1;
        if (c + 1 < c1) {
            const int k1 = nbase + (c + 1) * KC + kg * 8;
            nah0 = *(const short8v*)(pH0 + k1);
            nah1 = *(const short8v*)(pH1 + k1);
            nal0 = *(const short8v*)(pL0 + k1);
            nal1 = *(const short8v*)(pL1 + k1);
            WGEN(c + 1, cur ^ 1);
        }

#pragma unroll
        for (int ni = 0; ni < 6; ++ni) {
            short8v bv = *(const short8v*)&sW[cur][ni * 16 + lr][kg * 8];
            acc[0][ni] = __builtin_amdgcn_mfma_f32_16x16x32_bf16(cah0, bv, acc[0][ni], 0, 0, 0);
            acc[1][ni] = __builtin_amdgcn_mfma_f32_16x16x32_bf16(cah1, bv, acc[1][ni], 0, 0, 0);
            acc[0][ni] = __builtin_amdgcn_mfma_f32_16x16x32_bf16(cal0, bv, acc[0][ni], 0, 0, 0);
            acc[1][ni] = __builtin_amdgcn_mfma_f32_16x16x32_bf16(cal1, bv, acc[1][ni], 0, 0, 0);
        }
        __syncthreads();

        cah0 = nah0; cah1 = nah1; cal0 = nal0; cal1 = nal1;
        cur ^= 1;
    }

#pragma unroll
    for (int mi = 0; mi < 2; ++mi)
#pragma unroll
        for (int ni = 0; ni < 6; ++ni) {
            const int d0 = wid * 32 + mi * 16 + kg * 4;
            const int x  = ni * 16 + lr;
            float* op = out + (((size_t)b * DD + d0) * GG + y) * GG + x;
#pragma unroll
            for (int r = 0; r < 4; ++r)
                op[(size_t)r * GG * GG] = acc[mi][ni][r];
        }
}

extern "C" void kernel_launch(void* const* d_in, const int* in_sizes, int n_in,
                              void* d_out, int out_size, void* d_ws, size_t ws_size,
                              hipStream_t stream) {
    const float* feat = (const float*)d_in[0];
    const float* pos  = (const float*)d_in[1];
    const float* lsig = (const float*)d_in[4];

    const int N  = in_sizes[2];                        // 4096
    const int B  = out_size / (DD * GG * GG);          // 8
    const int n_per = N / B;                           // 512

    int* pref = (int*)d_ws;                            // B x 97
    int* src  = pref + B * (GG + 1);                   // N
    float* wygT = (float*)(src + N);                   // 96 x N f32
    float* wxT  = wygT + (size_t)GG * N;               // 96 x N f32
    unsigned short* fTh = (unsigned short*)(wxT + (size_t)GG * N);  // 128 x N bf16
    unsigned short* fTl = fTh + (size_t)DD * N;                     // 128 x N bf16

    sort_nodes<<<B, n_per, 0, stream>>>(pos, pref, src, n_per);
    node_weights_p<<<N / 32, 256, 0, stream>>>(pos, lsig, src, wygT, wxT, N);
    transpose_split_p<<<N / 32, 256, 0, stream>>>(feat, src, fTh, fTl, N);

    dim3 g2(B, GG);
    splat_mfma<<<g2, 256, 0, stream>>>(fTh, fTl, wygT, wxT, pref, (float*)d_out, N, n_per);
}

// Round 6
// 38.613 us; speedup vs baseline: 1.9776x; 1.1310x over previous
//
#include <hip/hip_runtime.h>
#include <hip/hip_bf16.h>

#define GG    96     // grid size
#define DD    128    // feature dim
#define KC    32     // K-chunk = MFMA K
#define APAD  40     // padded LDS row stride in ushorts (80 B)
#define RCUT  21     // gaussian support radius in rows (sigma=4: exp(-21^2/32)=1e-6)
#define NPER  512    // nodes per batch (N/B = 4096/8); preprocess assumes this

typedef __attribute__((ext_vector_type(8))) short short8v;  // 8 bf16 = 4 VGPRs
typedef __attribute__((ext_vector_type(4))) float f32x4;    // MFMA acc

// ---------------- Kernel 1: fused preprocess ----------------
// Grid: (N/32) blocks x 256 threads. Each block:
//   (a) redundantly counting-sorts its batch's 512 nodes by floor(py) in LDS
//       (ballot-rank, identical permutation to the former sort_nodes kernel),
//   (b) computes separable gaussian weights for its 32 sorted nodes -> wygT/wxT,
//   (c) gather-transposes f rows into bf16 hi/lo -> fTh/fTl.
// Blocks at j0loc==0 also write pref[b][0..96].
__global__ __launch_bounds__(256) void preprocess(
    const float* __restrict__ pos, const float* __restrict__ log_sigma,
    const float* __restrict__ f,
    int* __restrict__ pref,
    float* __restrict__ wygT, float* __restrict__ wxT,
    unsigned short* __restrict__ fTh, unsigned short* __restrict__ fTl,
    int Nn, int n_per)
{
    const int blk   = blockIdx.x;
    const int bpb   = NPER / 32;              // 16 blocks per batch
    const int b     = blk / bpb;
    const int j0loc = (blk % bpb) * 32;
    const int nbase = b * NPER;
    const int t     = (int)threadIdx.x;
    const int w     = t >> 6, lane = t & 63;

    __shared__ int ghist[8][GG];              // per-64-window bin counts
    __shared__ int gpart[8][GG];              // cross-window exclusive offsets
    __shared__ int spre[GG + 1];              // batch bin prefix
    __shared__ int inv[NPER];                 // sorted pos -> batch-local node
    __shared__ int sn[32];
    __shared__ float spy[32], spx[32], sG[32];
    __shared__ float sPy[8][32], sPx[8][32];
    __shared__ __align__(16) float ubig[GG * 32 * 2];   // 24 KiB, phased reuse
    float (*sE)[32] = (float(*)[32])ubig;               // weights phase
    float (*sX)[32] = (float(*)[32])(ubig + GG * 32);
    float (*sT)[33] = (float(*)[33])ubig;               // transpose phase

    // ---- (a) in-LDS counting sort of the whole batch ----
    for (int i = t; i < 8 * GG; i += 256) (&ghist[0][0])[i] = 0;
    __syncthreads();

    // thread t handles batch-local nodes t (window w) and t+256 (window 4+w)
    int binA, binB;
    {
        float pyA = pos[(size_t)(nbase + t) * 2];
        float pyB = pos[(size_t)(nbase + t + 256) * 2];
        binA = (int)floorf(pyA); binA = binA < 0 ? 0 : (binA > GG - 1 ? GG - 1 : binA);
        binB = (int)floorf(pyB); binB = binB < 0 ? 0 : (binB > GG - 1 ? GG - 1 : binB);
        atomicAdd(&ghist[w][binA], 1);
        atomicAdd(&ghist[4 + w][binB], 1);
    }
    const unsigned long long below = (lane == 0) ? 0ull : (~0ull >> (64 - lane));
    unsigned long long mA = ~0ull, mB = ~0ull;
#pragma unroll
    for (int bit = 0; bit < 7; ++bit) {
        unsigned long long bA = __ballot((binA >> bit) & 1);
        unsigned long long bB = __ballot((binB >> bit) & 1);
        mA &= ((binA >> bit) & 1) ? bA : ~bA;
        mB &= ((binB >> bit) & 1) ? bB : ~bB;
    }
    const int rA = __popcll(mA & below);
    const int rB = __popcll(mB & below);
    __syncthreads();

    if (t < GG) {
        int s = 0;
#pragma unroll
        for (int g = 0; g < 8; ++g) { gpart[g][t] = s; s += ghist[g][t]; }
        spre[t + 1] = s;
    }
    __syncthreads();
    if (t == 0) {
        int s = 0; spre[0] = 0;
        for (int i = 1; i <= GG; ++i) { s += spre[i]; spre[i] = s; }
    }
    __syncthreads();

    inv[spre[binA] + gpart[w][binA] + rA]     = t;
    inv[spre[binB] + gpart[4 + w][binB] + rB] = t + 256;
    if (j0loc == 0 && t < GG + 1) pref[b * (GG + 1) + t] = spre[t];
    __syncthreads();

    if (t < 32) {
        int nl = inv[j0loc + t];
        sn[t]  = nl;
        spy[t] = pos[(size_t)(nbase + nl) * 2 + 0];
        spx[t] = pos[(size_t)(nbase + nl) * 2 + 1];
    }
    __syncthreads();

    // ---- (b) separable weights for 32 sorted nodes ----
    const int g = t >> 5, c = t & 31;
    const float sig = expf(log_sigma[0]);
    const float inv2s2 = 1.0f / (2.0f * sig * sig);
    const float py = spy[c], px = spx[c];

    float pey = 0.f, pex = 0.f;
#pragma unroll
    for (int r = 0; r < 12; ++r) {
        int yy = r * 8 + g;
        float dy = (float)yy - py;
        float dx = (float)yy - px;
        float ey = expf(-dy * dy * inv2s2);
        float ex = expf(-dx * dx * inv2s2);
        sE[yy][c] = ey; sX[yy][c] = ex;
        pey += ey; pex += ex;
    }
    sPy[g][c] = pey; sPx[g][c] = pex;
    __syncthreads();

    if (t < 32) {
        float sy = 0.f, sx = 0.f;
#pragma unroll
        for (int ww = 0; ww < 8; ++ww) { sy += sPy[ww][t]; sx += sPx[ww][t]; }
        sG[t] = 1.0f / (sy * sx + 1e-8f);
    }
    __syncthreads();

    const float gf = sG[c];
    const int jcol = nbase + j0loc;           // global permuted column base
#pragma unroll
    for (int r = 0; r < 12; ++r) {
        int yy = r * 8 + g;
        wygT[(size_t)yy * Nn + jcol + c] = sE[yy][c] * gf;
        wxT [(size_t)yy * Nn + jcol + c] = sX[yy][c];
    }
    __syncthreads();   // before sT overwrites ubig

    // ---- (c) gather-transpose-split f -> bf16 hi/lo ----
#pragma unroll
    for (int jj = 0; jj < 4; ++jj) {
        int idx = t + 256 * jj;               // 0..1023
        int nl  = idx >> 5;                   // 0..31
        int cc  = idx & 31;                   // float4 column
        float4 v = *(const float4*)(f + (size_t)(nbase + sn[nl]) * DD + cc * 4);
        sT[cc * 4 + 0][nl] = v.x;
        sT[cc * 4 + 1][nl] = v.y;
        sT[cc * 4 + 2][nl] = v.z;
        sT[cc * 4 + 3][nl] = v.w;
    }
    __syncthreads();

    const int d = t >> 1, h = t & 1;
    unsigned int ph[8], pl[8];
#pragma unroll
    for (int q = 0; q < 8; ++q) {
        float x0 = sT[d][h * 16 + 2 * q];
        float x1 = sT[d][h * 16 + 2 * q + 1];
        __hip_bfloat16 h0 = __float2bfloat16(x0);
        __hip_bfloat16 h1 = __float2bfloat16(x1);
        __hip_bfloat16 l0 = __float2bfloat16(x0 - __bfloat162float(h0));
        __hip_bfloat16 l1 = __float2bfloat16(x1 - __bfloat162float(h1));
        unsigned short uh0 = *(const unsigned short*)&h0;
        unsigned short uh1 = *(const unsigned short*)&h1;
        unsigned short ul0 = *(const unsigned short*)&l0;
        unsigned short ul1 = *(const unsigned short*)&l1;
        ph[q] = (unsigned int)uh0 | ((unsigned int)uh1 << 16);
        pl[q] = (unsigned int)ul0 | ((unsigned int)ul1 << 16);
    }
    int4* dh = (int4*)(fTh + (size_t)d * Nn + jcol + h * 16);
    int4* dl = (int4*)(fTl + (size_t)d * Nn + jcol + h * 16);
    dh[0] = make_int4((int)ph[0], (int)ph[1], (int)ph[2], (int)ph[3]);
    dh[1] = make_int4((int)ph[4], (int)ph[5], (int)ph[6], (int)ph[7]);
    dl[0] = make_int4((int)pl[0], (int)pl[1], (int)pl[2], (int)pl[3]);
    dl[1] = make_int4((int)pl[4], (int)pl[5], (int)pl[6], (int)pl[7]);
}

// ---------------- Kernel 2: MFMA splat GEMM (unchanged from validated R5) ----------------
__global__ __launch_bounds__(256, 3) void splat_mfma(
    const unsigned short* __restrict__ fTh, const unsigned short* __restrict__ fTl,
    const float* __restrict__ wygT, const float* __restrict__ wxT,
    const int* __restrict__ pref,
    float* __restrict__ out, int Nn, int n_per)
{
    const int b = blockIdx.x;
    const int y = blockIdx.y;
    const int tid = (int)threadIdx.x;
    const int lane = tid & 63;
    const int wid  = tid >> 6;
    const int lr = lane & 15;
    const int kg = lane >> 4;

    __shared__ __align__(16) unsigned short sW[2][GG][APAD];  // 15 KiB dbuf

    f32x4 acc[2][6];
#pragma unroll
    for (int mi = 0; mi < 2; ++mi)
#pragma unroll
        for (int ni = 0; ni < 6; ++ni) acc[mi][ni] = (f32x4){0.f, 0.f, 0.f, 0.f};

    const int lob = y - RCUT < 0 ? 0 : y - RCUT;
    const int hib = y + RCUT > GG ? GG : y + RCUT;
    const int klo = pref[b * (GG + 1) + lob];
    const int khi = pref[b * (GG + 1) + hib];
    const int c0 = klo >> 5;
    const int c1 = (khi + 31) >> 5;

    const int nbase = b * n_per;
    const float* wyrow = wygT + (size_t)y * Nn;

    const int ar0 = wid * 32 + lr;
    const unsigned short* pH0 = fTh + (size_t)ar0 * Nn;
    const unsigned short* pH1 = fTh + (size_t)(ar0 + 16) * Nn;
    const unsigned short* pL0 = fTl + (size_t)ar0 * Nn;
    const unsigned short* pL1 = fTl + (size_t)(ar0 + 16) * Nn;

#define WGEN(CC, BUF)                                                              \
    {                                                                              \
        const int ncur_ = nbase + (CC) * KC;                                       \
        _Pragma("unroll")                                                          \
        for (int i_ = 0; i_ < 6; ++i_) {                                           \
            int p_  = tid + 256 * i_;                                              \
            int x_  = p_ >> 4;                                                     \
            int kp_ = p_ & 15;                                                     \
            float2 wy_ = *(const float2*)(wyrow + ncur_ + 2 * kp_);                \
            float2 wx_ = *(const float2*)(wxT + (size_t)x_ * Nn + ncur_ + 2 * kp_);\
            float w0_ = wy_.x * wx_.x, w1_ = wy_.y * wx_.y;                        \
            __hip_bfloat16 b0_ = __float2bfloat16(w0_);                            \
            __hip_bfloat16 b1_ = __float2bfloat16(w1_);                            \
            unsigned int u_ = (unsigned int)(*(const unsigned short*)&b0_)         \
                            | ((unsigned int)(*(const unsigned short*)&b1_) << 16);\
            *(unsigned int*)&sW[BUF][x_][2 * kp_] = u_;                            \
        }                                                                          \
    }

    short8v cah0 = {}, cah1 = {}, cal0 = {}, cal1 = {};
    if (c0 < c1) {
        WGEN(c0, 0);
        const int k0 = nbase + c0 * KC + kg * 8;
        cah0 = *(const short8v*)(pH0 + k0);
        cah1 = *(const short8v*)(pH1 + k0);
        cal0 = *(const short8v*)(pL0 + k0);
        cal1 = *(const short8v*)(pL1 + k0);
    }
    __syncthreads();

    int cur = 0;
    for (int c = c0; c < c1; ++c) {
        short8v nah0 = cah0, nah1 = cah1, nal0 = cal0, nal1 = cal1;
        if (c + 1 < c1) {
            const int k1 = nbase + (c + 1) * KC + kg * 8;
            nah0 = *(const short8v*)(pH0 + k1);
            nah1 = *(const short8v*)(pH1 + k1);
            nal0 = *(const short8v*)(pL0 + k1);
            nal1 = *(const short8v*)(pL1 + k1);
            WGEN(c + 1, cur ^ 1);
        }

#pragma unroll
        for (int ni = 0; ni < 6; ++ni) {
            short8v bv = *(const short8v*)&sW[cur][ni * 16 + lr][kg * 8];
            acc[0][ni] = __builtin_amdgcn_mfma_f32_16x16x32_bf16(cah0, bv, acc[0][ni], 0, 0, 0);
            acc[1][ni] = __builtin_amdgcn_mfma_f32_16x16x32_bf16(cah1, bv, acc[1][ni], 0, 0, 0);
            acc[0][ni] = __builtin_amdgcn_mfma_f32_16x16x32_bf16(cal0, bv, acc[0][ni], 0, 0, 0);
            acc[1][ni] = __builtin_amdgcn_mfma_f32_16x16x32_bf16(cal1, bv, acc[1][ni], 0, 0, 0);
        }
        __syncthreads();

        cah0 = nah0; cah1 = nah1; cal0 = nal0; cal1 = nal1;
        cur ^= 1;
    }

#pragma unroll
    for (int mi = 0; mi < 2; ++mi)
#pragma unroll
        for (int ni = 0; ni < 6; ++ni) {
            const int d0 = wid * 32 + mi * 16 + kg * 4;
            const int x  = ni * 16 + lr;
            float* op = out + (((size_t)b * DD + d0) * GG + y) * GG + x;
#pragma unroll
            for (int r = 0; r < 4; ++r)
                op[(size_t)r * GG * GG] = acc[mi][ni][r];
        }
}

extern "C" void kernel_launch(void* const* d_in, const int* in_sizes, int n_in,
                              void* d_out, int out_size, void* d_ws, size_t ws_size,
                              hipStream_t stream) {
    const float* feat = (const float*)d_in[0];
    const float* pos  = (const float*)d_in[1];
    const float* lsig = (const float*)d_in[4];

    const int N  = in_sizes[2];                        // 4096
    const int B  = out_size / (DD * GG * GG);          // 8
    const int n_per = N / B;                           // 512 (== NPER)

    int* pref = (int*)d_ws;                            // B x 97
    float* wygT = (float*)(pref + B * (GG + 1));       // 96 x N f32
    float* wxT  = wygT + (size_t)GG * N;               // 96 x N f32
    unsigned short* fTh = (unsigned short*)(wxT + (size_t)GG * N);  // 128 x N bf16
    unsigned short* fTl = fTh + (size_t)DD * N;                     // 128 x N bf16

    preprocess<<<N / 32, 256, 0, stream>>>(pos, lsig, feat, pref, wygT, wxT, fTh, fTl, N, n_per);

    dim3 g2(B, GG);
    splat_mfma<<<g2, 256, 0, stream>>>(fTh, fTl, wygT, wxT, pref, (float*)d_out, N, n_per);
}

// Round 7
// 33.756 us; speedup vs baseline: 2.2621x; 1.1439x over previous
//
#include <hip/hip_runtime.h>
#include <hip/hip_bf16.h>

#define GG    96     // grid size
#define DD    128    // feature dim
#define KC    32     // K-chunk = MFMA K
#define APAD  40     // padded LDS row stride in ushorts (80 B)
#define RCUT  21     // gaussian support radius in rows (sigma=4: exp(-21^2/32)=1e-6)
#define NPER  512    // nodes per batch (N/B)
#define NPB   16     // nodes per preprocess block

typedef __attribute__((ext_vector_type(8))) short short8v;  // 8 bf16 = 4 VGPRs
typedef __attribute__((ext_vector_type(4))) float f32x4;    // MFMA acc

// ---------------- Kernel 1: fused preprocess (16 nodes/block, 256 blocks) ----------------
__global__ __launch_bounds__(256) void preprocess(
    const float* __restrict__ pos, const float* __restrict__ log_sigma,
    const float* __restrict__ f,
    int* __restrict__ pref,
    float* __restrict__ wygT, float* __restrict__ wxT,
    unsigned short* __restrict__ fTh, unsigned short* __restrict__ fTl,
    int Nn)
{
    const int blk   = blockIdx.x;
    const int bpb   = NPER / NPB;             // 32 blocks per batch
    const int b     = blk / bpb;
    const int j0loc = (blk % bpb) * NPB;
    const int nbase = b * NPER;
    const int t     = (int)threadIdx.x;
    const int w     = t >> 6, lane = t & 63;

    __shared__ int ghist[8][GG];
    __shared__ int gpart[8][GG];
    __shared__ int spre[GG + 1];
    __shared__ int inv[NPER];
    __shared__ int sn[NPB];
    __shared__ float spy[NPB], spx[NPB], sG[NPB];
    __shared__ float sPy[16][NPB], sPx[16][NPB];
    __shared__ __align__(16) float ubig[GG * NPB * 2];   // 12 KiB, phased reuse
    float (*sE)[NPB] = (float(*)[NPB])ubig;              // weights phase
    float (*sX)[NPB] = (float(*)[NPB])(ubig + GG * NPB);
    float (*sT)[17]  = (float(*)[17])ubig;               // transpose phase (128x17 f32)

    // ---- (a) in-LDS counting sort of the whole batch (redundant per block) ----
    for (int i = t; i < 8 * GG; i += 256) (&ghist[0][0])[i] = 0;
    __syncthreads();

    int binA, binB;
    {
        float pyA = pos[(size_t)(nbase + t) * 2];
        float pyB = pos[(size_t)(nbase + t + 256) * 2];
        binA = (int)floorf(pyA); binA = binA < 0 ? 0 : (binA > GG - 1 ? GG - 1 : binA);
        binB = (int)floorf(pyB); binB = binB < 0 ? 0 : (binB > GG - 1 ? GG - 1 : binB);
        atomicAdd(&ghist[w][binA], 1);
        atomicAdd(&ghist[4 + w][binB], 1);
    }
    const unsigned long long below = (lane == 0) ? 0ull : (~0ull >> (64 - lane));
    unsigned long long mA = ~0ull, mB = ~0ull;
#pragma unroll
    for (int bit = 0; bit < 7; ++bit) {
        unsigned long long bA = __ballot((binA >> bit) & 1);
        unsigned long long bB = __ballot((binB >> bit) & 1);
        mA &= ((binA >> bit) & 1) ? bA : ~bA;
        mB &= ((binB >> bit) & 1) ? bB : ~bB;
    }
    const int rA = __popcll(mA & below);
    const int rB = __popcll(mB & below);
    __syncthreads();

    if (t < GG) {
        int s = 0;
#pragma unroll
        for (int g = 0; g < 8; ++g) { gpart[g][t] = s; s += ghist[g][t]; }
        spre[t + 1] = s;
    }
    __syncthreads();
    if (t == 0) {
        int s = 0; spre[0] = 0;
        for (int i = 1; i <= GG; ++i) { s += spre[i]; spre[i] = s; }
    }
    __syncthreads();

    inv[spre[binA] + gpart[w][binA] + rA]     = t;
    inv[spre[binB] + gpart[4 + w][binB] + rB] = t + 256;
    if (j0loc == 0 && t < GG + 1) pref[b * (GG + 1) + t] = spre[t];
    __syncthreads();

    if (t < NPB) {
        int nl = inv[j0loc + t];
        sn[t]  = nl;
        spy[t] = pos[(size_t)(nbase + nl) * 2 + 0];
        spx[t] = pos[(size_t)(nbase + nl) * 2 + 1];
    }
    __syncthreads();

    // ---- (b) separable weights for NPB sorted nodes ----
    const int g = t >> 4, c = t & 15;        // g: 16 y-groups, c: node
    const float sig = expf(log_sigma[0]);
    const float inv2s2 = 1.0f / (2.0f * sig * sig);
    const float py = spy[c], px = spx[c];

    float pey = 0.f, pex = 0.f;
#pragma unroll
    for (int r = 0; r < 6; ++r) {
        int yy = r * 16 + g;
        float dy = (float)yy - py;
        float dx = (float)yy - px;
        float ey = expf(-dy * dy * inv2s2);
        float ex = expf(-dx * dx * inv2s2);
        sE[yy][c] = ey; sX[yy][c] = ex;
        pey += ey; pex += ex;
    }
    sPy[g][c] = pey; sPx[g][c] = pex;
    __syncthreads();

    if (t < NPB) {
        float sy = 0.f, sx = 0.f;
#pragma unroll
        for (int gg = 0; gg < 16; ++gg) { sy += sPy[gg][t]; sx += sPx[gg][t]; }
        sG[t] = 1.0f / (sy * sx + 1e-8f);
    }
    __syncthreads();

    const float gf = sG[c];
    const int jcol = nbase + j0loc;
#pragma unroll
    for (int r = 0; r < 6; ++r) {
        int yy = r * 16 + g;
        wygT[(size_t)yy * Nn + jcol + c] = sE[yy][c] * gf;
        wxT [(size_t)yy * Nn + jcol + c] = sX[yy][c];
    }
    __syncthreads();   // before sT overwrites ubig

    // ---- (c) gather-transpose-split f -> bf16 hi/lo ----
#pragma unroll
    for (int jj = 0; jj < 2; ++jj) {
        int idx = t + 256 * jj;               // 0..511
        int nl  = idx >> 5;                   // 0..15
        int cc  = idx & 31;                   // float4 column
        float4 v = *(const float4*)(f + (size_t)(nbase + sn[nl]) * DD + cc * 4);
        sT[cc * 4 + 0][nl] = v.x;
        sT[cc * 4 + 1][nl] = v.y;
        sT[cc * 4 + 2][nl] = v.z;
        sT[cc * 4 + 3][nl] = v.w;
    }
    __syncthreads();

    const int d = t >> 1, h = t & 1;          // d row, 8-element half
    unsigned int ph[4], pl[4];
#pragma unroll
    for (int q = 0; q < 4; ++q) {
        float x0 = sT[d][h * 8 + 2 * q];
        float x1 = sT[d][h * 8 + 2 * q + 1];
        __hip_bfloat16 h0 = __float2bfloat16(x0);
        __hip_bfloat16 h1 = __float2bfloat16(x1);
        __hip_bfloat16 l0 = __float2bfloat16(x0 - __bfloat162float(h0));
        __hip_bfloat16 l1 = __float2bfloat16(x1 - __bfloat162float(h1));
        unsigned short uh0 = *(const unsigned short*)&h0;
        unsigned short uh1 = *(const unsigned short*)&h1;
        unsigned short ul0 = *(const unsigned short*)&l0;
        unsigned short ul1 = *(const unsigned short*)&l1;
        ph[q] = (unsigned int)uh0 | ((unsigned int)uh1 << 16);
        pl[q] = (unsigned int)ul0 | ((unsigned int)ul1 << 16);
    }
    *(int4*)(fTh + (size_t)d * Nn + jcol + h * 8) = make_int4((int)ph[0], (int)ph[1], (int)ph[2], (int)ph[3]);
    *(int4*)(fTl + (size_t)d * Nn + jcol + h * 8) = make_int4((int)pl[0], (int)pl[1], (int)pl[2], (int)pl[3]);
}

// ---------------- Kernel 2: MFMA splat GEMM, XCD-swizzled, packed cvt, no A-prefetch ----------------
__global__ __launch_bounds__(256, 3) void splat_mfma(
    const unsigned short* __restrict__ fTh, const unsigned short* __restrict__ fTl,
    const float* __restrict__ wygT, const float* __restrict__ wxT,
    const int* __restrict__ pref,
    float* __restrict__ out, int Nn, int n_per)
{
    // 768 blocks; XCD-chunked swizzle: XCD x owns batch x (y-major within batch).
    const int swz = ((int)blockIdx.x % 8) * (GG * 8 / 8) + (int)blockIdx.x / 8;
    const int b = swz / GG;
    const int y = swz % GG;
    const int tid = (int)threadIdx.x;
    const int lane = tid & 63;
    const int wid  = tid >> 6;
    const int lr = lane & 15;
    const int kg = lane >> 4;

    __shared__ __align__(16) unsigned short sW[2][GG][APAD];  // 15 KiB dbuf

    f32x4 acc[2][6];
#pragma unroll
    for (int mi = 0; mi < 2; ++mi)
#pragma unroll
        for (int ni = 0; ni < 6; ++ni) acc[mi][ni] = (f32x4){0.f, 0.f, 0.f, 0.f};

    const int lob = y - RCUT < 0 ? 0 : y - RCUT;
    const int hib = y + RCUT > GG ? GG : y + RCUT;
    const int klo = pref[b * (GG + 1) + lob];
    const int khi = pref[b * (GG + 1) + hib];
    const int c0 = klo >> 5;
    const int c1 = (khi + 31) >> 5;

    const int nbase = b * n_per;
    const float* wyrow = wygT + (size_t)y * Nn;

    const int ar0 = wid * 32 + lr;
    const unsigned short* pH0 = fTh + (size_t)ar0 * Nn;
    const unsigned short* pH1 = fTh + (size_t)(ar0 + 16) * Nn;
    const unsigned short* pL0 = fTl + (size_t)ar0 * Nn;
    const unsigned short* pL1 = fTl + (size_t)(ar0 + 16) * Nn;

#define WGEN(CC, BUF)                                                              \
    {                                                                              \
        const int ncur_ = nbase + (CC) * KC;                                       \
        _Pragma("unroll")                                                          \
        for (int i_ = 0; i_ < 6; ++i_) {                                           \
            int p_  = tid + 256 * i_;                                              \
            int x_  = p_ >> 4;                                                     \
            int kp_ = p_ & 15;                                                     \
            float2 wy_ = *(const float2*)(wyrow + ncur_ + 2 * kp_);                \
            float2 wx_ = *(const float2*)(wxT + (size_t)x_ * Nn + ncur_ + 2 * kp_);\
            __hip_bfloat162 bb_ = __float22bfloat162_rn(                           \
                make_float2(wy_.x * wx_.x, wy_.y * wx_.y));                        \
            *(unsigned int*)&sW[BUF][x_][2 * kp_] = *(unsigned int*)&bb_;          \
        }                                                                          \
    }

    if (c0 < c1) WGEN(c0, 0);
    __syncthreads();

    int cur = 0;
    for (int c = c0; c < c1; ++c) {
        // A fragments for this chunk (L2-hot; latency hidden under WGEN + TLP)
        const int k0 = nbase + c * KC + kg * 8;
        short8v cah0 = *(const short8v*)(pH0 + k0);
        short8v cah1 = *(const short8v*)(pH1 + k0);
        short8v cal0 = *(const short8v*)(pL0 + k0);
        short8v cal1 = *(const short8v*)(pL1 + k0);

        if (c + 1 < c1) WGEN(c + 1, cur ^ 1);

#pragma unroll
        for (int ni = 0; ni < 6; ++ni) {
            short8v bv = *(const short8v*)&sW[cur][ni * 16 + lr][kg * 8];
            acc[0][ni] = __builtin_amdgcn_mfma_f32_16x16x32_bf16(cah0, bv, acc[0][ni], 0, 0, 0);
            acc[1][ni] = __builtin_amdgcn_mfma_f32_16x16x32_bf16(cah1, bv, acc[1][ni], 0, 0, 0);
            acc[0][ni] = __builtin_amdgcn_mfma_f32_16x16x32_bf16(cal0, bv, acc[0][ni], 0, 0, 0);
            acc[1][ni] = __builtin_amdgcn_mfma_f32_16x16x32_bf16(cal1, bv, acc[1][ni], 0, 0, 0);
        }
        __syncthreads();
        cur ^= 1;
    }

#pragma unroll
    for (int mi = 0; mi < 2; ++mi)
#pragma unroll
        for (int ni = 0; ni < 6; ++ni) {
            const int d0 = wid * 32 + mi * 16 + kg * 4;
            const int x  = ni * 16 + lr;
            float* op = out + (((size_t)b * DD + d0) * GG + y) * GG + x;
#pragma unroll
            for (int r = 0; r < 4; ++r)
                op[(size_t)r * GG * GG] = acc[mi][ni][r];
        }
}

extern "C" void kernel_launch(void* const* d_in, const int* in_sizes, int n_in,
                              void* d_out, int out_size, void* d_ws, size_t ws_size,
                              hipStream_t stream) {
    const float* feat = (const float*)d_in[0];
    const float* pos  = (const float*)d_in[1];
    const float* lsig = (const float*)d_in[4];

    const int N  = in_sizes[2];                        // 4096
    const int B  = out_size / (DD * GG * GG);          // 8
    const int n_per = N / B;                           // 512 (== NPER)

    int* pref = (int*)d_ws;                            // B x 97
    float* wygT = (float*)(pref + B * (GG + 1));       // 96 x N f32
    float* wxT  = wygT + (size_t)GG * N;               // 96 x N f32
    unsigned short* fTh = (unsigned short*)(wxT + (size_t)GG * N);  // 128 x N bf16
    unsigned short* fTl = fTh + (size_t)DD * N;                     // 128 x N bf16

    preprocess<<<N / NPB, 256, 0, stream>>>(pos, lsig, feat, pref, wygT, wxT, fTh, fTl, N);

    splat_mfma<<<B * GG, 256, 0, stream>>>(fTh, fTl, wygT, wxT, pref, (float*)d_out, N, n_per);
}

// Round 8
// 33.319 us; speedup vs baseline: 2.2919x; 1.0131x over previous
//
#include <hip/hip_runtime.h>
#include <hip/hip_bf16.h>

#define GG    96     // grid size
#define DD    128    // feature dim
#define KC    32     // K-chunk = MFMA K
#define APAD  40     // padded LDS row stride in ushorts (80 B)
#define RCUT  21     // gaussian support radius in rows (sigma=4: exp(-21^2/32)=1e-6)
#define NPER  512    // nodes per batch (N/B)
#define NPB   16     // nodes per preprocess block

typedef __attribute__((ext_vector_type(8))) short short8v;  // 8 bf16 = 4 VGPRs
typedef __attribute__((ext_vector_type(4))) float f32x4;    // MFMA acc

// ---------------- Kernel 1: fused preprocess (16 nodes/block, 256 blocks) ----------------
__global__ __launch_bounds__(256) void preprocess(
    const float* __restrict__ pos, const float* __restrict__ log_sigma,
    const float* __restrict__ f,
    int* __restrict__ pref,
    float* __restrict__ wygT, float* __restrict__ wxT,
    unsigned short* __restrict__ fTh, unsigned short* __restrict__ fTl,
    int Nn)
{
    const int blk   = blockIdx.x;
    const int bpb   = NPER / NPB;             // 32 blocks per batch
    const int b     = blk / bpb;
    const int j0loc = (blk % bpb) * NPB;
    const int nbase = b * NPER;
    const int t     = (int)threadIdx.x;
    const int w     = t >> 6, lane = t & 63;

    __shared__ int ghist[8][GG];
    __shared__ int gpart[8][GG];
    __shared__ int spre[GG + 1];
    __shared__ int inv[NPER];
    __shared__ int sn[NPB];
    __shared__ int wtot;
    __shared__ float spy[NPB], spx[NPB], sG[NPB];
    __shared__ float sPy[16][NPB], sPx[16][NPB];
    __shared__ __align__(16) float ubig[GG * NPB * 2];   // 12 KiB, phased reuse
    float (*sE)[NPB] = (float(*)[NPB])ubig;              // weights phase
    float (*sX)[NPB] = (float(*)[NPB])(ubig + GG * NPB);
    float (*sT)[17]  = (float(*)[17])ubig;               // transpose phase (128x17 f32)

    // ---- (a) in-LDS counting sort of the whole batch (redundant per block) ----
    for (int i = t; i < 8 * GG; i += 256) (&ghist[0][0])[i] = 0;
    __syncthreads();

    int binA, binB;
    {
        float pyA = pos[(size_t)(nbase + t) * 2];
        float pyB = pos[(size_t)(nbase + t + 256) * 2];
        binA = (int)floorf(pyA); binA = binA < 0 ? 0 : (binA > GG - 1 ? GG - 1 : binA);
        binB = (int)floorf(pyB); binB = binB < 0 ? 0 : (binB > GG - 1 ? GG - 1 : binB);
        atomicAdd(&ghist[w][binA], 1);
        atomicAdd(&ghist[4 + w][binB], 1);
    }
    const unsigned long long below = (lane == 0) ? 0ull : (~0ull >> (64 - lane));
    unsigned long long mA = ~0ull, mB = ~0ull;
#pragma unroll
    for (int bit = 0; bit < 7; ++bit) {
        unsigned long long bA = __ballot((binA >> bit) & 1);
        unsigned long long bB = __ballot((binB >> bit) & 1);
        mA &= ((binA >> bit) & 1) ? bA : ~bA;
        mB &= ((binB >> bit) & 1) ? bB : ~bB;
    }
    const int rA = __popcll(mA & below);
    const int rB = __popcll(mB & below);
    __syncthreads();

    // per-bin cross-window offsets + bin count (register)
    int bc = 0;
    if (t < GG) {
        int s = 0;
#pragma unroll
        for (int g = 0; g < 8; ++g) { gpart[g][t] = s; s += ghist[g][t]; }
        bc = s;
    }
    // two-wave Kogge-Stone inclusive scan over the 96 bin counts (no serial chain)
    int xs = bc;
#pragma unroll
    for (int off = 1; off < 64; off <<= 1) {
        int v = __shfl_up(xs, off, 64);
        if (lane >= off) xs += v;
    }
    if (t == 63) wtot = xs;
    __syncthreads();
    if (t >= 64 && t < GG) xs += wtot;
    if (t < GG) spre[t + 1] = xs;
    if (t == 0) spre[0] = 0;
    __syncthreads();

    inv[spre[binA] + gpart[w][binA] + rA]     = t;
    inv[spre[binB] + gpart[4 + w][binB] + rB] = t + 256;
    if (j0loc == 0 && t < GG + 1) pref[b * (GG + 1) + t] = spre[t];
    __syncthreads();

    if (t < NPB) {
        int nl = inv[j0loc + t];
        sn[t]  = nl;
        spy[t] = pos[(size_t)(nbase + nl) * 2 + 0];
        spx[t] = pos[(size_t)(nbase + nl) * 2 + 1];
    }
    __syncthreads();

    // ---- (b) separable weights for NPB sorted nodes ----
    const int g = t >> 4, c = t & 15;        // g: 16 y-groups, c: node
    const float sig = expf(log_sigma[0]);
    const float inv2s2 = 1.0f / (2.0f * sig * sig);
    const float py = spy[c], px = spx[c];

    float pey = 0.f, pex = 0.f;
#pragma unroll
    for (int r = 0; r < 6; ++r) {
        int yy = r * 16 + g;
        float dy = (float)yy - py;
        float dx = (float)yy - px;
        float ey = expf(-dy * dy * inv2s2);
        float ex = expf(-dx * dx * inv2s2);
        sE[yy][c] = ey; sX[yy][c] = ex;
        pey += ey; pex += ex;
    }
    sPy[g][c] = pey; sPx[g][c] = pex;
    __syncthreads();

    if (t < NPB) {
        float sy = 0.f, sx = 0.f;
#pragma unroll
        for (int gg = 0; gg < 16; ++gg) { sy += sPy[gg][t]; sx += sPx[gg][t]; }
        sG[t] = 1.0f / (sy * sx + 1e-8f);
    }
    __syncthreads();

    const float gf = sG[c];
    const int jcol = nbase + j0loc;
#pragma unroll
    for (int r = 0; r < 6; ++r) {
        int yy = r * 16 + g;
        wygT[(size_t)yy * Nn + jcol + c] = sE[yy][c] * gf;
        wxT [(size_t)yy * Nn + jcol + c] = sX[yy][c];
    }
    __syncthreads();   // before sT overwrites ubig

    // ---- (c) gather-transpose-split f -> bf16 hi/lo ----
#pragma unroll
    for (int jj = 0; jj < 2; ++jj) {
        int idx = t + 256 * jj;               // 0..511
        int nl  = idx >> 5;                   // 0..15
        int cc  = idx & 31;                   // float4 column
        float4 v = *(const float4*)(f + (size_t)(nbase + sn[nl]) * DD + cc * 4);
        sT[cc * 4 + 0][nl] = v.x;
        sT[cc * 4 + 1][nl] = v.y;
        sT[cc * 4 + 2][nl] = v.z;
        sT[cc * 4 + 3][nl] = v.w;
    }
    __syncthreads();

    const int d = t >> 1, h = t & 1;          // d row, 8-element half
    unsigned int ph[4], pl[4];
#pragma unroll
    for (int q = 0; q < 4; ++q) {
        float x0 = sT[d][h * 8 + 2 * q];
        float x1 = sT[d][h * 8 + 2 * q + 1];
        __hip_bfloat16 h0 = __float2bfloat16(x0);
        __hip_bfloat16 h1 = __float2bfloat16(x1);
        __hip_bfloat16 l0 = __float2bfloat16(x0 - __bfloat162float(h0));
        __hip_bfloat16 l1 = __float2bfloat16(x1 - __bfloat162float(h1));
        unsigned short uh0 = *(const unsigned short*)&h0;
        unsigned short uh1 = *(const unsigned short*)&h1;
        unsigned short ul0 = *(const unsigned short*)&l0;
        unsigned short ul1 = *(const unsigned short*)&l1;
        ph[q] = (unsigned int)uh0 | ((unsigned int)uh1 << 16);
        pl[q] = (unsigned int)ul0 | ((unsigned int)ul1 << 16);
    }
    *(int4*)(fTh + (size_t)d * Nn + jcol + h * 8) = make_int4((int)ph[0], (int)ph[1], (int)ph[2], (int)ph[3]);
    *(int4*)(fTl + (size_t)d * Nn + jcol + h * 8) = make_int4((int)pl[0], (int)pl[1], (int)pl[2], (int)pl[3]);
}

// ---------------- Kernel 2: MFMA splat GEMM, XCD-swizzled, nt epilogue ----------------
__global__ __launch_bounds__(256, 3) void splat_mfma(
    const unsigned short* __restrict__ fTh, const unsigned short* __restrict__ fTl,
    const float* __restrict__ wygT, const float* __restrict__ wxT,
    const int* __restrict__ pref,
    float* __restrict__ out, int Nn, int n_per)
{
    // 768 blocks; XCD-chunked swizzle: XCD x owns batch x (y-major within batch).
    const int swz = ((int)blockIdx.x % 8) * (GG * 8 / 8) + (int)blockIdx.x / 8;
    const int b = swz / GG;
    const int y = swz % GG;
    const int tid = (int)threadIdx.x;
    const int lane = tid & 63;
    const int wid  = tid >> 6;
    const int lr = lane & 15;
    const int kg = lane >> 4;

    __shared__ __align__(16) unsigned short sW[2][GG][APAD];  // 15 KiB dbuf

    f32x4 acc[2][6];
#pragma unroll
    for (int mi = 0; mi < 2; ++mi)
#pragma unroll
        for (int ni = 0; ni < 6; ++ni) acc[mi][ni] = (f32x4){0.f, 0.f, 0.f, 0.f};

    const int lob = y - RCUT < 0 ? 0 : y - RCUT;
    const int hib = y + RCUT > GG ? GG : y + RCUT;
    const int klo = pref[b * (GG + 1) + lob];
    const int khi = pref[b * (GG + 1) + hib];
    const int c0 = klo >> 5;
    const int c1 = (khi + 31) >> 5;

    const int nbase = b * n_per;
    const float* wyrow = wygT + (size_t)y * Nn;

    const int ar0 = wid * 32 + lr;
    const unsigned short* pH0 = fTh + (size_t)ar0 * Nn;
    const unsigned short* pH1 = fTh + (size_t)(ar0 + 16) * Nn;
    const unsigned short* pL0 = fTl + (size_t)ar0 * Nn;
    const unsigned short* pL1 = fTl + (size_t)(ar0 + 16) * Nn;

#define WGEN(CC, BUF)                                                              \
    {                                                                              \
        const int ncur_ = nbase + (CC) * KC;                                       \
        _Pragma("unroll")                                                          \
        for (int i_ = 0; i_ < 6; ++i_) {                                           \
            int p_  = tid + 256 * i_;                                              \
            int x_  = p_ >> 4;                                                     \
            int kp_ = p_ & 15;                                                     \
            float2 wy_ = *(const float2*)(wyrow + ncur_ + 2 * kp_);                \
            float2 wx_ = *(const float2*)(wxT + (size_t)x_ * Nn + ncur_ + 2 * kp_);\
            __hip_bfloat162 bb_ = __float22bfloat162_rn(                           \
                make_float2(wy_.x * wx_.x, wy_.y * wx_.y));                        \
            *(unsigned int*)&sW[BUF][x_][2 * kp_] = *(unsigned int*)&bb_;          \
        }                                                                          \
    }

    if (c0 < c1) WGEN(c0, 0);
    __syncthreads();

    int cur = 0;
    for (int c = c0; c < c1; ++c) {
        // A fragments for this chunk (issued before WGEN -> latency hidden under it)
        const int k0 = nbase + c * KC + kg * 8;
        short8v cah0 = *(const short8v*)(pH0 + k0);
        short8v cah1 = *(const short8v*)(pH1 + k0);
        short8v cal0 = *(const short8v*)(pL0 + k0);
        short8v cal1 = *(const short8v*)(pL1 + k0);

        if (c + 1 < c1) WGEN(c + 1, cur ^ 1);

#pragma unroll
        for (int ni = 0; ni < 6; ++ni) {
            short8v bv = *(const short8v*)&sW[cur][ni * 16 + lr][kg * 8];
            acc[0][ni] = __builtin_amdgcn_mfma_f32_16x16x32_bf16(cah0, bv, acc[0][ni], 0, 0, 0);
            acc[1][ni] = __builtin_amdgcn_mfma_f32_16x16x32_bf16(cah1, bv, acc[1][ni], 0, 0, 0);
            acc[0][ni] = __builtin_amdgcn_mfma_f32_16x16x32_bf16(cal0, bv, acc[0][ni], 0, 0, 0);
            acc[1][ni] = __builtin_amdgcn_mfma_f32_16x16x32_bf16(cal1, bv, acc[1][ni], 0, 0, 0);
        }
        __syncthreads();
        cur ^= 1;
    }

    // nt epilogue: output is write-once, never re-read -> bypass L2 (keep operands resident)
#pragma unroll
    for (int mi = 0; mi < 2; ++mi)
#pragma unroll
        for (int ni = 0; ni < 6; ++ni) {
            const int d0 = wid * 32 + mi * 16 + kg * 4;
            const int x  = ni * 16 + lr;
            float* op = out + (((size_t)b * DD + d0) * GG + y) * GG + x;
#pragma unroll
            for (int r = 0; r < 4; ++r)
                __builtin_nontemporal_store(acc[mi][ni][r], op + (size_t)r * GG * GG);
        }
}

extern "C" void kernel_launch(void* const* d_in, const int* in_sizes, int n_in,
                              void* d_out, int out_size, void* d_ws, size_t ws_size,
                              hipStream_t stream) {
    const float* feat = (const float*)d_in[0];
    const float* pos  = (const float*)d_in[1];
    const float* lsig = (const float*)d_in[4];

    const int N  = in_sizes[2];                        // 4096
    const int B  = out_size / (DD * GG * GG);          // 8
    const int n_per = N / B;                           // 512 (== NPER)

    int* pref = (int*)d_ws;                            // B x 97
    float* wygT = (float*)(pref + B * (GG + 1));       // 96 x N f32
    float* wxT  = wygT + (size_t)GG * N;               // 96 x N f32
    unsigned short* fTh = (unsigned short*)(wxT + (size_t)GG * N);  // 128 x N bf16
    unsigned short* fTl = fTh + (size_t)DD * N;                     // 128 x N bf16

    preprocess<<<N / NPB, 256, 0, stream>>>(pos, lsig, feat, pref, wygT, wxT, fTh, fTl, N);

    splat_mfma<<<B * GG, 256, 0, stream>>>(fTh, fTl, wygT, wxT, pref, (float*)d_out, N, n_per);
}